// Round 4
// baseline (4338.019 us; speedup 1.0000x reference)
//
#include <hip/hip_runtime.h>
#include <hip/hip_bf16.h>
#include <math.h>

typedef __hip_bfloat16 bf16;
__device__ __forceinline__ float b2f(bf16 x){ return __bfloat162float(x); }
__device__ __forceinline__ bf16 f2b(float x){ return __float2bfloat16(x); }

// dtype-generic load: inputs may be f32 (per the reference) or bf16.
__device__ __forceinline__ float ld(const void* p, size_t i, bool f32) {
    return f32 ? ((const float*)p)[i] : __bfloat162float(((const bf16*)p)[i]);
}

// One workgroup per (n,b). Zero workspace usage: everything lives in LDS.
__global__ __launch_bounds__(256) void mega_kernel(
    const void* __restrict__ sentence,   // [2048, 24, 512]
    const void* __restrict__ sent_sum,   // [2048, 512]
    const int*  __restrict__ mask,       // [2048, 24]
    const void* __restrict__ Wk, const void* __restrict__ bk,
    const void* __restrict__ Wv, const void* __restrict__ bv,
    const void* __restrict__ Wq, const void* __restrict__ bq,
    const void* __restrict__ g_ln, const void* __restrict__ b_ln,
    const void* __restrict__ W1, const void* __restrict__ b1,
    const void* __restrict__ W2, const void* __restrict__ b2,
    const void* __restrict__ Wbind, const void* __restrict__ bbind,
    const void* __restrict__ Wproj, const void* __restrict__ bproj,
    void* __restrict__ out)              // [2048, 8, 256]
{
    const int W = 24, S = 8, D = 256, IN = 512, H = 512;
    __shared__ float seh[2048];          // 8KB: ssum | sentence chunk f32[24][64] | hh
    __shared__ bf16  kk[24 * 256];       // 12KB
    __shared__ bf16  vv[24 * 256];       // 12KB
    __shared__ float is0s[8 * 256];      //  8KB
    __shared__ float sl[8 * 256];        //  8KB  slots
    __shared__ float qv[8 * 256];        //  8KB  q, later upd
    __shared__ float attn[24][8];
    __shared__ float colsum[8], mean_s[8], rstd_s[8], maskf[24];

    int nb = blockIdx.x;
    int t  = threadIdx.x;

    // ---- dtype detection (block-uniform; reads sentence[0..63]) ----
    bool f32in = false;
    {
        const bf16* probe = (const bf16*)sentence;
        #pragma unroll
        for (int i = 0; i < 64; i++) {
            float x = __bfloat162float(probe[i]);
            if (!(fabsf(x) < 1e4f)) f32in = true;   // catches huge/NaN/inf
        }
    }

    size_t sbase = (size_t)nb * W * IN;

    // ---- stage ssum (f32 in seh) + maskf ----
    if (t < W) maskf[t] = mask[(size_t)nb * W + t] ? 0.f : -1e6f;
    for (int l = t; l < IN; l += 256) seh[l] = ld(sent_sum, (size_t)nb * IN + l, f32in);
    __syncthreads();

    // ---- initial slots: thread t -> is0[j][t] ----
    {
        float acc[S];
        #pragma unroll
        for (int j = 0; j < S; j++) acc[j] = ld(bbind, j * D + t, f32in);
        for (int c = 0; c < IN; c++) {
            float sc = seh[c];
            #pragma unroll
            for (int j = 0; j < S; j++)
                acc[j] += sc * ld(Wbind, (size_t)c * (S * D) + j * D + t, f32in);
        }
        #pragma unroll
        for (int j = 0; j < S; j++) {
            is0s[j * D + t] = acc[j];
            sl[j * D + t]   = acc[j];
        }
    }

    // ---- k, v projections: sentence streamed in 8 f32 chunks of [24][64] ----
    {
        float ka[W], va[W];
        float bkv = ld(bk, t, f32in), bvv = ld(bv, t, f32in);
        #pragma unroll
        for (int i = 0; i < W; i++) { ka[i] = bkv; va[i] = bvv; }
        for (int ch = 0; ch < 8; ch++) {
            __syncthreads();   // protect seh (prev readers done)
            for (int l = t; l < W * 64; l += 256) {
                int i = l >> 6, c = l & 63;
                seh[l] = ld(sentence, sbase + (size_t)i * IN + ch * 64 + c, f32in);
            }
            __syncthreads();
            for (int c = 0; c < 64; c++) {
                int cg = ch * 64 + c;
                float wk = ld(Wk, (size_t)cg * D + t, f32in);
                float wv = ld(Wv, (size_t)cg * D + t, f32in);
                #pragma unroll
                for (int i = 0; i < W; i++) {
                    float s = seh[i * 64 + c];
                    ka[i] += s * wk;
                    va[i] += s * wv;
                }
            }
        }
        #pragma unroll
        for (int i = 0; i < W; i++) {
            float kx = ka[i];
            kk[i * D + t] = f2b(kx > 0.f ? kx + 1.f : expf(kx));  // elu+1
            vv[i * D + t] = f2b(va[i]);
        }
    }
    __syncthreads();

    // ---- 3 slot-attention iterations ----
    for (int it = 0; it < 3; it++) {
        // q = elu((sl@Wq + bq + is0) / 16) + 1   (thread t = dim)
        {
            float qa[S];
            float bqv = ld(bq, t, f32in);
            #pragma unroll
            for (int j = 0; j < S; j++) qa[j] = bqv + is0s[j * D + t];
            for (int c = 0; c < D; c++) {
                float wq = ld(Wq, (size_t)c * D + t, f32in);
                #pragma unroll
                for (int j = 0; j < S; j++) qa[j] += sl[j * D + c] * wq;
            }
            #pragma unroll
            for (int j = 0; j < S; j++) {
                float y = qa[j] * 0.0625f;
                qv[j * D + t] = y > 0.f ? y + 1.f : expf(y);
            }
        }
        __syncthreads();

        // logits = k.q + maskf
        if (t < W * S) {
            int i = t >> 3, j = t & 7;
            float a = 0.f;
            #pragma unroll 8
            for (int d = 0; d < D; d++)
                a += b2f(kk[i * D + d]) * qv[j * D + d];
            attn[i][j] = a + maskf[i];
        }
        __syncthreads();

        // softmax over slots (+eps)
        if (t < W) {
            float m = attn[t][0];
            #pragma unroll
            for (int j = 1; j < S; j++) m = fmaxf(m, attn[t][j]);
            float e[S]; float s = 0.f;
            #pragma unroll
            for (int j = 0; j < S; j++) { e[j] = expf(attn[t][j] - m); s += e[j]; }
            #pragma unroll
            for (int j = 0; j < S; j++) attn[t][j] = e[j] / s + 1e-6f;
        }
        __syncthreads();

        if (t < S) {
            float s = 0.f;
            for (int i = 0; i < W; i++) s += attn[i][t];
            colsum[t] = s;
        }
        __syncthreads();

        // updates (word-renorm folded); qv region becomes 'upd'
        {
            float acc[S] = {};
            #pragma unroll
            for (int i = 0; i < W; i++) {
                float vx = b2f(vv[i * D + t]);
                #pragma unroll
                for (int j = 0; j < S; j++) acc[j] += attn[i][j] * vx;
            }
            #pragma unroll
            for (int j = 0; j < S; j++) qv[j * D + t] = acc[j] / colsum[j];
        }
        __syncthreads();

        // LayerNorm stats: wave w handles slots 2w, 2w+1
        {
            int lane = t & 63;
            #pragma unroll
            for (int jj = 0; jj < 2; jj++) {
                int j = (t >> 6) * 2 + jj;
                float x0 = qv[j * D + lane],       x1 = qv[j * D + lane + 64];
                float x2 = qv[j * D + lane + 128], x3 = qv[j * D + lane + 192];
                float p = x0 + x1 + x2 + x3;
                for (int off = 32; off; off >>= 1) p += __shfl_xor(p, off);
                float mean = p * (1.f / 256.f);
                float d0 = x0 - mean, d1 = x1 - mean, d2 = x2 - mean, d3 = x3 - mean;
                float vr = d0 * d0 + d1 * d1 + d2 * d2 + d3 * d3;
                for (int off = 32; off; off >>= 1) vr += __shfl_xor(vr, off);
                if (lane == 0) {
                    mean_s[j] = mean;
                    rstd_s[j] = rsqrtf(vr * (1.f / 256.f) + 1e-5f);
                }
            }
        }
        __syncthreads();

        // normalize in place
        {
            float g = ld(g_ln, t, f32in), bb = ld(b_ln, t, f32in);
            #pragma unroll
            for (int j = 0; j < S; j++)
                qv[j * D + t] = (qv[j * D + t] - mean_s[j]) * rstd_s[j] * g + bb;
        }
        __syncthreads();

        // MLP in two hidden-halves; hh lives in seh (8KB)
        {
            float sa[S];
            float b2v = ld(b2, t, f32in);
            #pragma unroll
            for (int j = 0; j < S; j++) sa[j] = b2v;
            for (int half = 0; half < 2; half++) {
                int hcol = half * 256 + t;
                float ha[S];
                float b1v = ld(b1, hcol, f32in);
                #pragma unroll
                for (int j = 0; j < S; j++) ha[j] = b1v;
                for (int d = 0; d < D; d++) {
                    float w1 = ld(W1, (size_t)d * H + hcol, f32in);
                    #pragma unroll
                    for (int j = 0; j < S; j++) ha[j] += qv[j * D + d] * w1;
                }
                __syncthreads();   // prev seh readers done
                #pragma unroll
                for (int j = 0; j < S; j++) seh[j * D + t] = fmaxf(ha[j], 0.f);
                __syncthreads();
                for (int h = 0; h < 256; h++) {
                    float w2 = ld(W2, (size_t)(half * 256 + h) * D + t, f32in);
                    #pragma unroll
                    for (int j = 0; j < S; j++) sa[j] += seh[j * D + h] * w2;
                }
            }
            __syncthreads();
            #pragma unroll
            for (int j = 0; j < S; j++)
                sl[j * D + t] += sa[j] * (1.f / 256.f);
        }
        __syncthreads();
    }

    // ---- out = concat(is0, slots) @ Wproj + bproj ----
    {
        float oa[S];
        float bpv = ld(bproj, t, f32in);
        #pragma unroll
        for (int j = 0; j < S; j++) oa[j] = bpv;
        for (int c = 0; c < D; c++) {
            float wp1 = ld(Wproj, (size_t)c * D + t, f32in);
            float wp2 = ld(Wproj, (size_t)(D + c) * D + t, f32in);
            #pragma unroll
            for (int j = 0; j < S; j++)
                oa[j] += is0s[j * D + c] * wp1 + sl[j * D + c] * wp2;
        }
        #pragma unroll
        for (int j = 0; j < S; j++) {
            size_t idx = (size_t)nb * (S * D) + j * D + t;
            if (f32in) ((float*)out)[idx] = oa[j];
            else       ((bf16*)out)[idx] = f2b(oa[j]);
        }
    }
}

extern "C" void kernel_launch(void* const* d_in, const int* in_sizes, int n_in,
                              void* d_out, int out_size, void* d_ws, size_t ws_size,
                              hipStream_t stream)
{
    mega_kernel<<<dim3(2048), dim3(256), 0, stream>>>(
        d_in[0], d_in[1], (const int*)d_in[2],
        d_in[3], d_in[4], d_in[5], d_in[6], d_in[7], d_in[8],
        d_in[9], d_in[10], d_in[11], d_in[12], d_in[13], d_in[14],
        d_in[15], d_in[16], d_in[17], d_in[18], d_out);
}

// Round 5
// 608.661 us; speedup vs baseline: 7.1271x; 7.1271x over previous
//
#include <hip/hip_runtime.h>
#include <hip/hip_bf16.h>
#include <math.h>

typedef unsigned int uint;
typedef unsigned short ushort;
typedef __attribute__((ext_vector_type(8))) short bf16x8;
typedef __attribute__((ext_vector_type(4))) float f32x4;

__device__ __forceinline__ float bu2f(ushort u){ union{uint u; float f;} v; v.u = ((uint)u)<<16; return v.f; }
__device__ __forceinline__ ushort f2bu(float x){ union{float f; uint u;} v; v.f = x; uint r = (v.u + 0x7FFFu + ((v.u>>16)&1u))>>16; return (ushort)r; }

#define GEPI_IS0  0
#define GEPI_KV   1
#define GEPI_Q    2
#define GEPI_RELU 3
#define GEPI_MLP2 4
#define GEPI_OUT  5

// C[M,N] = A[M,K(lda)] @ Bt[N,K]^T + bias, bf16 MFMA 16x16x32, tile 128x128x32.
// 256 threads = 4 waves (2x2), each wave 64x64 via 4x4 MFMA tiles.
template<int EPI, bool AF32>
__global__ __launch_bounds__(256) void mfma_gemm(
    const void* __restrict__ Aptr, int lda,
    const ushort* __restrict__ Bt,
    const float* __restrict__ xb0, const float* __restrict__ xb1,
    const float* __restrict__ xf,
    float* __restrict__ fp0, float* __restrict__ fp1,
    ushort* __restrict__ up0, ushort* __restrict__ up1,
    int M, int N, int K)
{
    __shared__ ushort As[128 * 40];   // +8 bf16 pad per row
    __shared__ ushort Bs[128 * 40];
    int tid  = threadIdx.x;
    int wave = tid >> 6, lane = tid & 63;
    int wr = wave >> 1, wc = wave & 1;
    int quad = lane >> 4, l15 = lane & 15;
    int row0 = blockIdx.y * 128, col0 = blockIdx.x * 128;
    int sr = tid >> 1, sc = (tid & 1) * 16;

    f32x4 acc[4][4];
    #pragma unroll
    for (int i = 0; i < 4; i++)
        #pragma unroll
        for (int j = 0; j < 4; j++) acc[i][j] = (f32x4){0.f, 0.f, 0.f, 0.f};

    for (int k0 = 0; k0 < K; k0 += 32) {
        if (AF32) {
            const float* A = (const float*)Aptr + (size_t)(row0 + sr) * lda + k0 + sc;
            uint p[8];
            #pragma unroll
            for (int i = 0; i < 4; i++) {
                float4 f = *(const float4*)(A + i * 4);
                p[2*i]   = (uint)f2bu(f.x) | ((uint)f2bu(f.y) << 16);
                p[2*i+1] = (uint)f2bu(f.z) | ((uint)f2bu(f.w) << 16);
            }
            uint4 u0; u0.x=p[0]; u0.y=p[1]; u0.z=p[2]; u0.w=p[3];
            uint4 u1; u1.x=p[4]; u1.y=p[5]; u1.z=p[6]; u1.w=p[7];
            *(uint4*)&As[sr * 40 + sc]     = u0;
            *(uint4*)&As[sr * 40 + sc + 8] = u1;
        } else {
            const ushort* A = (const ushort*)Aptr + (size_t)(row0 + sr) * lda + k0 + sc;
            uint4 a0 = *(const uint4*)A;
            uint4 a1 = *(const uint4*)(A + 8);
            *(uint4*)&As[sr * 40 + sc]     = a0;
            *(uint4*)&As[sr * 40 + sc + 8] = a1;
        }
        {
            const ushort* B = Bt + (size_t)(col0 + sr) * K + k0 + sc;
            uint4 b0 = *(const uint4*)B;
            uint4 b1 = *(const uint4*)(B + 8);
            *(uint4*)&Bs[sr * 40 + sc]     = b0;
            *(uint4*)&Bs[sr * 40 + sc + 8] = b1;
        }
        __syncthreads();
        bf16x8 af[4], bfr[4];
        #pragma unroll
        for (int mt = 0; mt < 4; mt++)
            af[mt] = *(const bf16x8*)&As[(wr * 64 + mt * 16 + l15) * 40 + quad * 8];
        #pragma unroll
        for (int nt = 0; nt < 4; nt++)
            bfr[nt] = *(const bf16x8*)&Bs[(wc * 64 + nt * 16 + l15) * 40 + quad * 8];
        #pragma unroll
        for (int mt = 0; mt < 4; mt++)
            #pragma unroll
            for (int nt = 0; nt < 4; nt++)
                acc[mt][nt] = __builtin_amdgcn_mfma_f32_16x16x32_bf16(
                    af[mt], bfr[nt], acc[mt][nt], 0, 0, 0);
        __syncthreads();
    }

    #pragma unroll
    for (int mt = 0; mt < 4; mt++) {
        #pragma unroll
        for (int nt = 0; nt < 4; nt++) {
            #pragma unroll
            for (int reg = 0; reg < 4; reg++) {
                int gr = row0 + wr * 64 + mt * 16 + quad * 4 + reg;
                int gc = col0 + wc * 64 + nt * 16 + l15;
                float x = acc[mt][nt][reg];
                if (EPI == GEPI_IS0) {
                    x += xb0[gc];
                    size_t i = (size_t)gr * N + gc;
                    fp0[i] = x; fp1[i] = x;
                    up0[((size_t)gr * 8 + (gc >> 8)) * 512 + (gc & 255)] = f2bu(x);
                } else if (EPI == GEPI_KV) {
                    if (gc < 256) {
                        x += xb0[gc];
                        x = x > 0.f ? x + 1.f : expf(x);
                        up0[(size_t)gr * 256 + gc] = f2bu(x);
                    } else {
                        x += xb1[gc - 256];
                        up1[(size_t)gr * 256 + gc - 256] = f2bu(x);
                    }
                } else if (EPI == GEPI_Q) {
                    x += xb0[gc];
                    float y = (x + xf[(size_t)gr * 256 + gc]) * 0.0625f;
                    y = y > 0.f ? y + 1.f : expf(y);
                    fp0[(size_t)gr * 256 + gc] = y;           // qbuf f32
                } else if (EPI == GEPI_RELU) {
                    x += xb0[gc];
                    up0[(size_t)gr * 512 + gc] = f2bu(fmaxf(x, 0.f));
                } else if (EPI == GEPI_MLP2) {
                    x += xb0[gc];
                    size_t i = (size_t)gr * 256 + gc;
                    float s = fp0[i] + x * (1.f / 256.f);
                    fp0[i] = s;
                    up0[(size_t)gr * 512 + 256 + gc] = f2bu(s);
                } else {  // GEPI_OUT
                    x += xb0[gc];
                    fp0[(size_t)gr * 256 + gc] = x;
                }
            }
        }
    }
}

// Convert + transpose all weights f32 -> bf16 [N][K]. 6912 blocks x 256 = 1,769,472.
__global__ __launch_bounds__(256) void prep_kernel(
    const float* __restrict__ Wbind, const float* __restrict__ Wk,
    const float* __restrict__ Wv, const float* __restrict__ Wq,
    const float* __restrict__ W1, const float* __restrict__ W2,
    const float* __restrict__ Wproj,
    ushort* __restrict__ Wbind_t, ushort* __restrict__ Wkv_t,
    ushort* __restrict__ Wq_t, ushort* __restrict__ W1_t,
    ushort* __restrict__ W2_t, ushort* __restrict__ Wproj_t)
{
    int idx = blockIdx.x * 256 + threadIdx.x;
    if (idx < 1048576) { int n = idx >> 9, k = idx & 511;
        Wbind_t[idx] = f2bu(Wbind[(size_t)k * 2048 + n]); return; }
    idx -= 1048576;
    if (idx < 262144) { int n = idx >> 9, k = idx & 511;
        Wkv_t[idx] = f2bu(n < 256 ? Wk[(size_t)k * 256 + n] : Wv[(size_t)k * 256 + n - 256]); return; }
    idx -= 262144;
    if (idx < 65536) { int n = idx >> 8, k = idx & 255;
        Wq_t[idx] = f2bu(Wq[(size_t)k * 256 + n]); return; }
    idx -= 65536;
    if (idx < 131072) { int n = idx >> 8, k = idx & 255;
        W1_t[idx] = f2bu(W1[(size_t)k * 512 + n]); return; }
    idx -= 131072;
    if (idx < 131072) { int n = idx >> 9, k = idx & 511;
        W2_t[idx] = f2bu(W2[(size_t)k * 256 + n]); return; }
    idx -= 131072;
    if (idx < 131072) { int n = idx >> 9, k = idx & 511;
        Wproj_t[idx] = f2bu(Wproj[(size_t)k * 256 + n]); return; }
}

// Per-(n,b): logits -> softmax(+eps) -> word renorm -> update -> LayerNorm -> ubuf bf16.
__global__ __launch_bounds__(256) void attn_kernel(
    const ushort* __restrict__ kbuf, const ushort* __restrict__ vbuf,
    const float* __restrict__ qbuf, const int* __restrict__ mask,
    const float* __restrict__ g_ln, const float* __restrict__ b_ln,
    ushort* __restrict__ ubuf)
{
    const int W = 24, S = 8;
    __shared__ ushort kk[24 * 256], vv[24 * 256];
    __shared__ float qs[8 * 257], us[8 * 257];
    __shared__ float attnw[24][8];
    __shared__ float colsum[8], mean_s[8], rstd_s[8], maskf[24];

    int nb = blockIdx.x, t = threadIdx.x;
    size_t bw = (size_t)nb * W * 256, bs = (size_t)nb * S * 256;

    for (int l = t; l < 3072; l += 256) {
        ((uint*)kk)[l] = ((const uint*)(kbuf + bw))[l];
        ((uint*)vv)[l] = ((const uint*)(vbuf + bw))[l];
    }
    for (int l = t; l < 2048; l += 256)
        qs[(l >> 8) * 257 + (l & 255)] = qbuf[bs + l];
    if (t < W) maskf[t] = mask[(size_t)nb * W + t] ? 0.f : -1e6f;
    __syncthreads();

    if (t < W * S) {
        int i = t >> 3, j = t & 7;
        float a = 0.f;
        #pragma unroll 8
        for (int d = 0; d < 256; d++) a += bu2f(kk[i * 256 + d]) * qs[j * 257 + d];
        attnw[i][j] = a + maskf[i];
    }
    __syncthreads();

    if (t < W) {
        float m = attnw[t][0];
        #pragma unroll
        for (int j = 1; j < S; j++) m = fmaxf(m, attnw[t][j]);
        float e[S]; float s = 0.f;
        #pragma unroll
        for (int j = 0; j < S; j++) { e[j] = expf(attnw[t][j] - m); s += e[j]; }
        #pragma unroll
        for (int j = 0; j < S; j++) attnw[t][j] = e[j] / s + 1e-6f;
    }
    __syncthreads();

    if (t < S) {
        float s = 0.f;
        for (int i = 0; i < W; i++) s += attnw[i][t];
        colsum[t] = s;
    }
    __syncthreads();

    {
        float acc[S] = {};
        #pragma unroll
        for (int i = 0; i < W; i++) {
            float vx = bu2f(vv[i * 256 + t]);
            #pragma unroll
            for (int j = 0; j < S; j++) acc[j] += attnw[i][j] * vx;
        }
        #pragma unroll
        for (int j = 0; j < S; j++) us[j * 257 + t] = acc[j] / colsum[j];
    }
    __syncthreads();

    {
        int lane = t & 63;
        #pragma unroll
        for (int jj = 0; jj < 2; jj++) {
            int j = (t >> 6) * 2 + jj;
            float x0 = us[j * 257 + lane],       x1 = us[j * 257 + lane + 64];
            float x2 = us[j * 257 + lane + 128], x3 = us[j * 257 + lane + 192];
            float p = x0 + x1 + x2 + x3;
            for (int off = 32; off; off >>= 1) p += __shfl_xor(p, off);
            float mean = p * (1.f / 256.f);
            float d0 = x0 - mean, d1 = x1 - mean, d2 = x2 - mean, d3 = x3 - mean;
            float vr = d0 * d0 + d1 * d1 + d2 * d2 + d3 * d3;
            for (int off = 32; off; off >>= 1) vr += __shfl_xor(vr, off);
            if (lane == 0) {
                mean_s[j] = mean;
                rstd_s[j] = rsqrtf(vr * (1.f / 256.f) + 1e-5f);
            }
        }
    }
    __syncthreads();

    {
        float g = g_ln[t], bb = b_ln[t];
        #pragma unroll
        for (int j = 0; j < S; j++)
            ubuf[bs + j * 256 + t] = f2bu((us[j * 257 + t] - mean_s[j]) * rstd_s[j] * g + bb);
    }
}

// ---------------- fallback: round-4 proven mega-kernel (f32 inputs) ----------------
__global__ __launch_bounds__(256) void mega_kernel(
    const float* __restrict__ sentence, const float* __restrict__ sent_sum,
    const int*  __restrict__ mask,
    const float* __restrict__ Wk, const float* __restrict__ bk,
    const float* __restrict__ Wv, const float* __restrict__ bv,
    const float* __restrict__ Wq, const float* __restrict__ bq,
    const float* __restrict__ g_ln, const float* __restrict__ b_ln,
    const float* __restrict__ W1, const float* __restrict__ b1,
    const float* __restrict__ W2, const float* __restrict__ b2,
    const float* __restrict__ Wbind, const float* __restrict__ bbind,
    const float* __restrict__ Wproj, const float* __restrict__ bproj,
    float* __restrict__ out)
{
    const int W = 24, S = 8, D = 256, IN = 512, H = 512;
    __shared__ float seh[2048];
    __shared__ ushort kk[24 * 256];
    __shared__ ushort vv[24 * 256];
    __shared__ float is0s[8 * 256];
    __shared__ float sl[8 * 256];
    __shared__ float qv[8 * 256];
    __shared__ float attnw[24][8];
    __shared__ float colsum[8], mean_s[8], rstd_s[8], maskf[24];

    int nb = blockIdx.x, t = threadIdx.x;
    size_t sbase = (size_t)nb * W * IN;

    if (t < W) maskf[t] = mask[(size_t)nb * W + t] ? 0.f : -1e6f;
    for (int l = t; l < IN; l += 256) seh[l] = sent_sum[(size_t)nb * IN + l];
    __syncthreads();
    {
        float acc[S];
        #pragma unroll
        for (int j = 0; j < S; j++) acc[j] = bbind[j * D + t];
        for (int c = 0; c < IN; c++) {
            float sc = seh[c];
            #pragma unroll
            for (int j = 0; j < S; j++) acc[j] += sc * Wbind[(size_t)c * (S * D) + j * D + t];
        }
        #pragma unroll
        for (int j = 0; j < S; j++) { is0s[j * D + t] = acc[j]; sl[j * D + t] = acc[j]; }
    }
    {
        float ka[W], va[W];
        float bkv = bk[t], bvv = bv[t];
        #pragma unroll
        for (int i = 0; i < W; i++) { ka[i] = bkv; va[i] = bvv; }
        for (int ch = 0; ch < 8; ch++) {
            __syncthreads();
            for (int l = t; l < W * 64; l += 256) {
                int i = l >> 6, c = l & 63;
                seh[l] = sentence[sbase + (size_t)i * IN + ch * 64 + c];
            }
            __syncthreads();
            for (int c = 0; c < 64; c++) {
                int cg = ch * 64 + c;
                float wk = Wk[(size_t)cg * D + t];
                float wv = Wv[(size_t)cg * D + t];
                #pragma unroll
                for (int i = 0; i < W; i++) {
                    float s = seh[i * 64 + c];
                    ka[i] += s * wk; va[i] += s * wv;
                }
            }
        }
        #pragma unroll
        for (int i = 0; i < W; i++) {
            float kx = ka[i];
            kk[i * D + t] = f2bu(kx > 0.f ? kx + 1.f : expf(kx));
            vv[i * D + t] = f2bu(va[i]);
        }
    }
    __syncthreads();

    for (int it = 0; it < 3; it++) {
        {
            float qa[S]; float bqv = bq[t];
            #pragma unroll
            for (int j = 0; j < S; j++) qa[j] = bqv + is0s[j * D + t];
            for (int c = 0; c < D; c++) {
                float wq = Wq[(size_t)c * D + t];
                #pragma unroll
                for (int j = 0; j < S; j++) qa[j] += sl[j * D + c] * wq;
            }
            #pragma unroll
            for (int j = 0; j < S; j++) {
                float y = qa[j] * 0.0625f;
                qv[j * D + t] = y > 0.f ? y + 1.f : expf(y);
            }
        }
        __syncthreads();
        if (t < W * S) {
            int i = t >> 3, j = t & 7;
            float a = 0.f;
            #pragma unroll 8
            for (int d = 0; d < D; d++) a += bu2f(kk[i * D + d]) * qv[j * D + d];
            attnw[i][j] = a + maskf[i];
        }
        __syncthreads();
        if (t < W) {
            float m = attnw[t][0];
            #pragma unroll
            for (int j = 1; j < S; j++) m = fmaxf(m, attnw[t][j]);
            float e[S]; float s = 0.f;
            #pragma unroll
            for (int j = 0; j < S; j++) { e[j] = expf(attnw[t][j] - m); s += e[j]; }
            #pragma unroll
            for (int j = 0; j < S; j++) attnw[t][j] = e[j] / s + 1e-6f;
        }
        __syncthreads();
        if (t < S) {
            float s = 0.f;
            for (int i = 0; i < W; i++) s += attnw[i][t];
            colsum[t] = s;
        }
        __syncthreads();
        {
            float acc[S] = {};
            #pragma unroll
            for (int i = 0; i < W; i++) {
                float vx = bu2f(vv[i * D + t]);
                #pragma unroll
                for (int j = 0; j < S; j++) acc[j] += attnw[i][j] * vx;
            }
            #pragma unroll
            for (int j = 0; j < S; j++) qv[j * D + t] = acc[j] / colsum[j];
        }
        __syncthreads();
        {
            int lane = t & 63;
            #pragma unroll
            for (int jj = 0; jj < 2; jj++) {
                int j = (t >> 6) * 2 + jj;
                float x0 = qv[j * D + lane],       x1 = qv[j * D + lane + 64];
                float x2 = qv[j * D + lane + 128], x3 = qv[j * D + lane + 192];
                float p = x0 + x1 + x2 + x3;
                for (int off = 32; off; off >>= 1) p += __shfl_xor(p, off);
                float mean = p * (1.f / 256.f);
                float d0 = x0 - mean, d1 = x1 - mean, d2 = x2 - mean, d3 = x3 - mean;
                float vr = d0 * d0 + d1 * d1 + d2 * d2 + d3 * d3;
                for (int off = 32; off; off >>= 1) vr += __shfl_xor(vr, off);
                if (lane == 0) { mean_s[j] = mean; rstd_s[j] = rsqrtf(vr * (1.f / 256.f) + 1e-5f); }
            }
        }
        __syncthreads();
        {
            float g = g_ln[t], bb = b_ln[t];
            #pragma unroll
            for (int j = 0; j < S; j++)
                qv[j * D + t] = (qv[j * D + t] - mean_s[j]) * rstd_s[j] * g + bb;
        }
        __syncthreads();
        {
            float sa[S]; float b2v = b2[t];
            #pragma unroll
            for (int j = 0; j < S; j++) sa[j] = b2v;
            for (int half = 0; half < 2; half++) {
                int hcol = half * 256 + t;
                float ha[S]; float b1v = b1[hcol];
                #pragma unroll
                for (int j = 0; j < S; j++) ha[j] = b1v;
                for (int d = 0; d < D; d++) {
                    float w1 = W1[(size_t)d * H + hcol];
                    #pragma unroll
                    for (int j = 0; j < S; j++) ha[j] += qv[j * D + d] * w1;
                }
                __syncthreads();
                #pragma unroll
                for (int j = 0; j < S; j++) seh[j * D + t] = fmaxf(ha[j], 0.f);
                __syncthreads();
                for (int h = 0; h < 256; h++) {
                    float w2 = W2[(size_t)(half * 256 + h) * D + t];
                    #pragma unroll
                    for (int j = 0; j < S; j++) sa[j] += seh[j * D + h] * w2;
                }
            }
            __syncthreads();
            #pragma unroll
            for (int j = 0; j < S; j++) sl[j * D + t] += sa[j] * (1.f / 256.f);
        }
        __syncthreads();
    }
    {
        float oa[S]; float bpv = bproj[t];
        #pragma unroll
        for (int j = 0; j < S; j++) oa[j] = bpv;
        for (int c = 0; c < D; c++) {
            float wp1 = Wproj[(size_t)c * D + t];
            float wp2 = Wproj[(size_t)(D + c) * D + t];
            #pragma unroll
            for (int j = 0; j < S; j++)
                oa[j] += is0s[j * D + c] * wp1 + sl[j * D + c] * wp2;
        }
        #pragma unroll
        for (int j = 0; j < S; j++)
            out[(size_t)nb * (S * D) + j * D + t] = oa[j];
    }
}

extern "C" void kernel_launch(void* const* d_in, const int* in_sizes, int n_in,
                              void* d_out, int out_size, void* d_ws, size_t ws_size,
                              hipStream_t stream)
{
    const float* sentence = (const float*)d_in[0];
    const float* sent_sum = (const float*)d_in[1];
    const int*  mask      = (const int*)d_in[2];
    const float* Wk = (const float*)d_in[3];  const float* bk = (const float*)d_in[4];
    const float* Wv = (const float*)d_in[5];  const float* bv = (const float*)d_in[6];
    const float* Wq = (const float*)d_in[7];  const float* bq = (const float*)d_in[8];
    const float* g_ln = (const float*)d_in[9];  const float* b_ln = (const float*)d_in[10];
    const float* W1 = (const float*)d_in[11]; const float* b1 = (const float*)d_in[12];
    const float* W2 = (const float*)d_in[13]; const float* b2 = (const float*)d_in[14];
    const float* Wbind = (const float*)d_in[15]; const float* bbind = (const float*)d_in[16];
    const float* Wproj = (const float*)d_in[17]; const float* bproj = (const float*)d_in[18];
    float* out = (float*)d_out;

    const size_t WS_NEEDED = 146145280ULL;
    if (ws_size >= WS_NEEDED) {
        char* w = (char*)d_ws;
        float*  slots   = (float*) (w);
        float*  is0     = (float*) (w + 16777216);
        ushort* catb    = (ushort*)(w + 33554432);
        ushort* kbuf    = (ushort*)(w + 50331648);
        ushort* vbuf    = (ushort*)(w + 75497472);
        float*  qbuf    = (float*) (w + 100663296);
        ushort* ubuf    = (ushort*)(w + 117440512);
        ushort* hbuf    = (ushort*)(w + 125829120);
        ushort* Wbind_t = (ushort*)(w + 142606336);
        ushort* Wkv_t   = (ushort*)(w + 144703488);
        ushort* Wq_t    = (ushort*)(w + 145227776);
        ushort* W1_t    = (ushort*)(w + 145358848);
        ushort* W2_t    = (ushort*)(w + 145620992);
        ushort* Wproj_t = (ushort*)(w + 145883136);

        prep_kernel<<<dim3(6912), dim3(256), 0, stream>>>(
            Wbind, Wk, Wv, Wq, W1, W2, Wproj,
            Wbind_t, Wkv_t, Wq_t, W1_t, W2_t, Wproj_t);

        // is0 = sent_sum @ Wbind + bbind ; slots = is0 ; catb[:, :256] = bf16(is0)
        mfma_gemm<GEPI_IS0, true><<<dim3(16, 16), dim3(256), 0, stream>>>(
            sent_sum, 512, Wbind_t, bbind, nullptr, nullptr,
            is0, slots, catb, nullptr, 2048, 2048, 512);

        // k = elu(sentence@Wk+bk)+1 ; v = sentence@Wv+bv
        mfma_gemm<GEPI_KV, true><<<dim3(4, 384), dim3(256), 0, stream>>>(
            sentence, 512, Wkv_t, bk, bv, nullptr,
            nullptr, nullptr, kbuf, vbuf, 49152, 512, 512);

        for (int it = 0; it < 3; it++) {
            mfma_gemm<GEPI_Q, false><<<dim3(2, 128), dim3(256), 0, stream>>>(
                catb + 256, 512, Wq_t, bq, nullptr, is0,
                qbuf, nullptr, nullptr, nullptr, 16384, 256, 256);
            attn_kernel<<<dim3(2048), dim3(256), 0, stream>>>(
                kbuf, vbuf, qbuf, mask, g_ln, b_ln, ubuf);
            mfma_gemm<GEPI_RELU, false><<<dim3(4, 128), dim3(256), 0, stream>>>(
                ubuf, 256, W1_t, b1, nullptr, nullptr,
                nullptr, nullptr, hbuf, nullptr, 16384, 512, 256);
            mfma_gemm<GEPI_MLP2, false><<<dim3(2, 128), dim3(256), 0, stream>>>(
                hbuf, 512, W2_t, b2, nullptr, nullptr,
                slots, nullptr, catb, nullptr, 16384, 256, 512);
        }

        mfma_gemm<GEPI_OUT, false><<<dim3(2, 128), dim3(256), 0, stream>>>(
            catb, 512, Wproj_t, bproj, nullptr, nullptr,
            out, nullptr, nullptr, nullptr, 16384, 256, 512);
    } else {
        mega_kernel<<<dim3(2048), dim3(256), 0, stream>>>(
            sentence, sent_sum, mask, Wk, bk, Wv, bv, Wq, bq, g_ln, b_ln,
            W1, b1, W2, b2, Wbind, bbind, Wproj, bproj, out);
    }
}